// Round 8
// baseline (140.866 us; speedup 1.0000x reference)
//
#include <hip/hip_runtime.h>

// Problem constants
#define H   16
#define E   300
#define D   768
#define HD  48
#define QL  64
#define KL  64
#define NH  64          // n(4) * h(16)
#define ROWS 384        // 256 Q rows + 64 K + 64 V
#define SPLITK 12
#define NEG 12          // e-chunk count (12 x 25 = 300)
#define ECH 25          // e per mega block

// Workspace float offsets
#define OFF_PP 0                              // Ppart[12][384][768]
#define OFF_PF (SPLITK*ROWS*D)                // 3,538,944  Pf[384][768]
#define OFF_OP (OFF_PF + ROWS*D)              // 3,833,856  OP[12][nh][q][48]
// end = 6,193,152 floats = 24.8 MB

// ---------------------------------------------------------------------------
// K1: QKV projection.  BM=64, BN=128, BK=32, splitK=12 (K-chunk 64).
// grid (6 rowblk, 6 colblk, 12 ks) = 432 blocks (2/CU), 256 thr, 4x8 microtile.
// (verified R3-R5 code, unchanged)
// ---------------------------------------------------------------------------
__global__ __launch_bounds__(256, 2) void proj_kernel(
    const float* __restrict__ qin, const float* __restrict__ kin, const float* __restrict__ vin,
    const float* __restrict__ Wq, const float* __restrict__ Wk, const float* __restrict__ Wv,
    float* __restrict__ ws)
{
    const int rowblk = blockIdx.x;            // 0..5 (64 rows each)
    const int col0   = blockIdx.y * 128;      // 0..640
    const int ks     = blockIdx.z;            // 0..11
    const int kbase  = ks * 64;

    const float* W = (rowblk < 4) ? Wq : (rowblk == 4) ? Wk : Wv;

    __shared__ float XsT[32][68];             // [dk][row], padded
    __shared__ float Ws[32][128];             // [dk][col]

    const int tid = threadIdx.x;
    const int r0  = (tid >> 4) * 4;           // 0..60
    const int c0  = (tid & 15) * 8;           // 0..120

    float acc[4][8];
    #pragma unroll
    for (int i = 0; i < 4; i++)
        #pragma unroll
        for (int j = 0; j < 8; j++) acc[i][j] = 0.f;

    for (int kk2 = 0; kk2 < 64; kk2 += 32) {
        // stage X tile (64 rows x 32 dk), transposed
        #pragma unroll
        for (int it = 0; it < 2; it++) {
            const int idx = it * 256 + tid;   // 0..511
            const int row = idx >> 3;         // 0..63
            const int d4  = (idx & 7) * 4;    // 0..28
            const int grow = rowblk * 64 + row;
            const float* src = (grow < 256) ? (qin + grow * D)
                             : (grow < 320) ? (kin + (grow - 256) * D)
                                            : (vin + (grow - 320) * D);
            const float4 xv = *(const float4*)(src + kbase + kk2 + d4);
            XsT[d4 + 0][row] = xv.x; XsT[d4 + 1][row] = xv.y;
            XsT[d4 + 2][row] = xv.z; XsT[d4 + 3][row] = xv.w;
        }
        // stage W tile (32 dk x 128 cols)
        #pragma unroll
        for (int it = 0; it < 4; it++) {
            const int idx = it * 256 + tid;   // 0..1023
            const int dk  = idx >> 5;         // 0..31
            const int c4  = (idx & 31) * 4;   // 0..124
            *(float4*)&Ws[dk][c4] =
                *(const float4*)(W + (kbase + kk2 + dk) * D + col0 + c4);
        }
        __syncthreads();
        #pragma unroll
        for (int dk = 0; dk < 32; dk++) {
            const float4 x0 = *(const float4*)&XsT[dk][r0];
            const float4 w0 = *(const float4*)&Ws[dk][c0];
            const float4 w1 = *(const float4*)&Ws[dk][c0 + 4];
            const float xr[4] = {x0.x, x0.y, x0.z, x0.w};
            const float wc[8] = {w0.x, w0.y, w0.z, w0.w, w1.x, w1.y, w1.z, w1.w};
            #pragma unroll
            for (int i = 0; i < 4; i++)
                #pragma unroll
                for (int j = 0; j < 8; j++)
                    acc[i][j] = fmaf(xr[i], wc[j], acc[i][j]);
        }
        __syncthreads();
    }
    float* P = ws + OFF_PP + ks * (ROWS * D);
    #pragma unroll
    for (int i = 0; i < 4; i++) {
        float* base = P + (rowblk * 64 + r0 + i) * D + col0 + c0;
        *(float4*)(base)     = make_float4(acc[i][0], acc[i][1], acc[i][2], acc[i][3]);
        *(float4*)(base + 4) = make_float4(acc[i][4], acc[i][5], acc[i][6], acc[i][7]);
    }
}

// ---------------------------------------------------------------------------
// K2: sum 12 splitK partials + bias -> Pf.  grid 288 x 256, 4 floats/thread.
// (verified R0/R5 code, unchanged)
// ---------------------------------------------------------------------------
__global__ __launch_bounds__(256) void reduce_kernel(
    const float* __restrict__ bq, const float* __restrict__ bk, const float* __restrict__ bv,
    float* __restrict__ ws)
{
    const int idx = (blockIdx.x * 256 + threadIdx.x) * 4;   // < 294912
    const float* PP = ws + OFF_PP;
    float4 v = *(const float4*)(PP + idx);
    #pragma unroll
    for (int c = 1; c < SPLITK; c++) {
        const float4 p = *(const float4*)(PP + c * (ROWS * D) + idx);
        v.x += p.x; v.y += p.y; v.z += p.z; v.w += p.w;
    }
    const int row = idx / D, col = idx % D;
    const float* bias = (row < 256) ? bq : (row < 320) ? bk : bv;
    const float4 b = *(const float4*)(bias + col);
    v.x += b.x; v.y += b.y; v.z += b.z; v.w += b.w;
    *(float4*)(ws + OFF_PF + idx) = v;
}

// ---------------------------------------------------------------------------
// K3: mega (R5 body; LDS cut 61.4 -> 51.2 KB for 3 blocks/CU).
// Block = (nh, eg of 25 e).  Stage Q/K/mem -> B build -> barrier -> A build
// (As OVERLAYS dead KsT) -> e-loop -> sequential 1-buffer wave reduce ->
// out-partial -> OP[eg][nh].  grid (64,12) = 768 blocks = 3/CU.
// ---------------------------------------------------------------------------
__global__ __launch_bounds__(256, 3) void mega_kernel(
    const float* __restrict__ memo, float* __restrict__ ws)
{
    const int nh = blockIdx.x;
    const int eg = blockIdx.y;                // 0..11
    const int e0 = eg * ECH;
    const int ecnt = ECH;                     // 12 x 25 = 300 exact
    const int n = nh >> 4, h = nh & 15;
    const int tid = threadIdx.x;
    const int lane = tid & 63;                // k
    const int w = tid >> 6;                   // 0..3

    const float* Pf = ws + OFF_PF;

    __shared__ float U[8448];                 // 33.0 KB union region
    __shared__ float Bs[64][68];              // 17.4 KB  B [k][q]; later Vs overlay
    // total 51.2 KB -> 3 blocks/CU

    float* QsT = U;                           // [48][68]  3264 floats
    float* KsT = U + 3264;                    // [48][68]  3264 floats
    float* MsT = U + 6528;                    // [48][40]  1920 floats
    float* As  = U + 3264;                    // [25][64]  1600 floats (overlays KsT)

    // ---- stage Q,K slices (transposed) + mem chunk ----
    #pragma unroll
    for (int it = 0; it < 3; it++) {
        const int idx = it * 256 + tid;       // 0..767
        const int r  = idx / 12;              // 0..63
        const int d4 = (idx % 12) * 4;
        const float4 qv = *(const float4*)(Pf + (n * QL + r) * D + h * HD + d4);
        QsT[(d4 + 0) * 68 + r] = qv.x; QsT[(d4 + 1) * 68 + r] = qv.y;
        QsT[(d4 + 2) * 68 + r] = qv.z; QsT[(d4 + 3) * 68 + r] = qv.w;
        const float4 kv = *(const float4*)(Pf + (256 + r) * D + h * HD + d4);
        KsT[(d4 + 0) * 68 + r] = kv.x; KsT[(d4 + 1) * 68 + r] = kv.y;
        KsT[(d4 + 2) * 68 + r] = kv.z; KsT[(d4 + 3) * 68 + r] = kv.w;
    }
    for (int idx = tid; idx < ecnt * 12; idx += 256) {
        const int e  = idx / 12;
        const int d4 = (idx % 12) * 4;
        const float4 mv = *(const float4*)(memo + (e0 + e) * D + h * HD + d4);
        MsT[(d4 + 0) * 40 + e] = mv.x; MsT[(d4 + 1) * 40 + e] = mv.y;
        MsT[(d4 + 2) * 40 + e] = mv.z; MsT[(d4 + 3) * 40 + e] = mv.w;
    }
    __syncthreads();

    // ---- B[k][q] = sum_d K[k,d] * Q[q,d]  (4x4 microtile) ----
    {
        const int k0 = (tid >> 4) * 4;
        const int q0 = (tid & 15) * 4;
        float acc[4][4];
        #pragma unroll
        for (int i = 0; i < 4; i++)
            #pragma unroll
            for (int j = 0; j < 4; j++) acc[i][j] = 0.f;
        #pragma unroll 4
        for (int d = 0; d < HD; d++) {
            const float4 kf = *(const float4*)&KsT[d * 68 + k0];
            const float4 qf = *(const float4*)&QsT[d * 68 + q0];
            const float kk4[4] = {kf.x, kf.y, kf.z, kf.w};
            const float qq4[4] = {qf.x, qf.y, qf.z, qf.w};
            #pragma unroll
            for (int i = 0; i < 4; i++)
                #pragma unroll
                for (int j = 0; j < 4; j++)
                    acc[i][j] = fmaf(kk4[i], qq4[j], acc[i][j]);
        }
        #pragma unroll
        for (int i = 0; i < 4; i++)
            *(float4*)&Bs[k0 + i][q0] =
                make_float4(acc[i][0], acc[i][1], acc[i][2], acc[i][3]);
    }
    __syncthreads();                          // KsT fully consumed; As may overlay

    // ---- A[e][q] = sum_d mem[e,d] * Q[q,d]  (3x4 microtile, guard e<ecnt) ----
    {
        const int et = (tid >> 4) * 3;        // 0..45
        const int q0 = (tid & 15) * 4;
        float acc[3][4];
        #pragma unroll
        for (int i = 0; i < 3; i++)
            #pragma unroll
            for (int j = 0; j < 4; j++) acc[i][j] = 0.f;
        #pragma unroll 4
        for (int d = 0; d < HD; d++) {
            const float me0 = MsT[d * 40 + et + 0];
            const float me1 = MsT[d * 40 + et + 1];
            const float me2 = MsT[d * 40 + et + 2];
            const float4 qf = *(const float4*)&QsT[d * 68 + q0];
            const float mm3[3] = {me0, me1, me2};
            const float qq4[4] = {qf.x, qf.y, qf.z, qf.w};
            #pragma unroll
            for (int i = 0; i < 3; i++)
                #pragma unroll
                for (int j = 0; j < 4; j++)
                    acc[i][j] = fmaf(mm3[i], qq4[j], acc[i][j]);
        }
        #pragma unroll
        for (int i = 0; i < 3; i++)
            if (et + i < ecnt)
                *(float4*)&As[(et + i) * 64 + q0] =
                    make_float4(acc[i][0], acc[i][1], acc[i][2], acc[i][3]);
    }
    __syncthreads();

    // ---- B row -> registers (lane = k) ----
    float b[64];
    #pragma unroll
    for (int j = 0; j < 16; j++)
        *(float4*)&b[j * 4] = *(const float4*)&Bs[lane][j * 4];
    __syncthreads();                          // all b[] reads done before Vs overlay

    // ---- stage V into Bs region (overlay); latency hides under e-loop ----
    float* Vs = &Bs[0][0];                    // [64][52] layout (flat, stride 52)
    #pragma unroll
    for (int it = 0; it < 3; it++) {
        const int idx = it * 256 + tid;       // 0..767
        const int k  = idx / 12;
        const int d4 = (idx % 12) * 4;
        const float4 vv = *(const float4*)(Pf + (320 + k) * D + h * HD + d4);
        *(float4*)&Vs[k * 52 + d4] = vv;
    }

    // ---- e-loop (verified core) ----
    float s[64];
    #pragma unroll
    for (int j = 0; j < 64; j++) s[j] = 0.f;

    const int eBeg = (ecnt * w) >> 2;         // 0,6,12,18
    const int eEnd = (ecnt * (w + 1)) >> 2;   // 6,12,18,25
    for (int e = eBeg; e < eEnd; e++) {
        float m[64];
        #pragma unroll
        for (int j4 = 0; j4 < 16; j4++) {
            const float4 a = *(const float4*)&As[e * 64 + j4 * 4];  // broadcast
            m[j4 * 4 + 0] = fmaxf(a.x + b[j4 * 4 + 0], 0.f);
            m[j4 * 4 + 1] = fmaxf(a.y + b[j4 * 4 + 1], 0.f);
            m[j4 * 4 + 2] = fmaxf(a.z + b[j4 * 4 + 2], 0.f);
            m[j4 * 4 + 3] = fmaxf(a.w + b[j4 * 4 + 3], 0.f);
        }
        float p0 = 0.f, p1 = 0.f, p2 = 0.f, p3 = 0.f;
        #pragma unroll
        for (int j4 = 0; j4 < 16; j4++) {
            p0 += m[j4 * 4 + 0]; p1 += m[j4 * 4 + 1];
            p2 += m[j4 * 4 + 2]; p3 += m[j4 * 4 + 3];
        }
        const float p = (p0 + p1) + (p2 + p3);
        #pragma unroll
        for (int j = 0; j < 64; j++)
            s[j] = fmaf(m[j], p, s[j]);
    }

    // ---- sequential 1-buffer wave reduce (r = 16 KB in U; As dead) ----
    float* r = U;                             // [0, 4096)
    float* Ss = U + 4096;                     // [64][68] = 4352 -> [4096, 8448)
    __syncthreads();
    if (w == 2) {
        #pragma unroll
        for (int q = 0; q < 64; q++) r[q * 64 + lane] = s[q];
    }
    __syncthreads();
    if (w == 0) {
        #pragma unroll
        for (int q = 0; q < 64; q++) s[q] += r[q * 64 + lane];
    }
    __syncthreads();
    if (w == 3) {
        #pragma unroll
        for (int q = 0; q < 64; q++) r[q * 64 + lane] = s[q];
    }
    __syncthreads();
    if (w == 1) {
        #pragma unroll
        for (int q = 0; q < 64; q++) s[q] += r[q * 64 + lane];
    }
    __syncthreads();
    if (w == 1) {
        #pragma unroll
        for (int q = 0; q < 64; q++) r[q * 64 + lane] = s[q];
    }
    __syncthreads();
    if (w == 0) {
        #pragma unroll
        for (int q = 0; q < 64; q++)
            Ss[q * 68 + lane] = s[q] + r[q * 64 + lane];
    }
    __syncthreads();

    // ---- out-partial[q][48] = sum_k Ss[q][k] * Vs[k][*] ----
    {
        const int q  = tid >> 2;              // 0..63
        const int dg = tid & 3;               // 0..3 (12 d each)
        float4 a0 = make_float4(0.f, 0.f, 0.f, 0.f);
        float4 a1 = a0, a2 = a0;
        #pragma unroll 8
        for (int k = 0; k < KL; k++) {
            const float sv = Ss[q * 68 + k];
            const float4 v0 = *(const float4*)&Vs[k * 52 + dg * 12 + 0];
            const float4 v1 = *(const float4*)&Vs[k * 52 + dg * 12 + 4];
            const float4 v2 = *(const float4*)&Vs[k * 52 + dg * 12 + 8];
            a0.x = fmaf(sv, v0.x, a0.x); a0.y = fmaf(sv, v0.y, a0.y);
            a0.z = fmaf(sv, v0.z, a0.z); a0.w = fmaf(sv, v0.w, a0.w);
            a1.x = fmaf(sv, v1.x, a1.x); a1.y = fmaf(sv, v1.y, a1.y);
            a1.z = fmaf(sv, v1.z, a1.z); a1.w = fmaf(sv, v1.w, a1.w);
            a2.x = fmaf(sv, v2.x, a2.x); a2.y = fmaf(sv, v2.y, a2.y);
            a2.z = fmaf(sv, v2.z, a2.z); a2.w = fmaf(sv, v2.w, a2.w);
        }
        float* OP = ws + OFF_OP + (((eg * NH) + nh) * QL + q) * 48 + dg * 12;
        *(float4*)(OP + 0) = a0;
        *(float4*)(OP + 4) = a1;
        *(float4*)(OP + 8) = a2;
    }
}

// ---------------------------------------------------------------------------
// K4: out = sum of 12 out-partials.  grid 192 x 256, one float4/thread.
// (verified R5 code; NEG now 12)
// ---------------------------------------------------------------------------
__global__ __launch_bounds__(256) void outsum_kernel(
    const float* __restrict__ ws_c, float* __restrict__ outp)
{
    const int g = blockIdx.x * 256 + threadIdx.x;   // 0..49151
    const int d12 = g % 12;
    const int q   = (g / 12) & 63;
    const int nh  = g / 768;                        // 0..63
    const int n = nh >> 4, h = nh & 15;
    const float* OP = ws_c + OFF_OP;

    float4 acc = make_float4(0.f, 0.f, 0.f, 0.f);
    #pragma unroll
    for (int c = 0; c < NEG; c++) {
        const float4 p = *(const float4*)(OP + c * (NH * QL * 48)
                                          + (nh * QL + q) * 48 + d12 * 4);
        acc.x += p.x; acc.y += p.y; acc.z += p.z; acc.w += p.w;
    }
    *(float4*)(outp + (n * QL + q) * D + h * HD + d12 * 4) = acc;
}

// ---------------------------------------------------------------------------
extern "C" void kernel_launch(void* const* d_in, const int* in_sizes, int n_in,
                              void* d_out, int out_size, void* d_ws, size_t ws_size,
                              hipStream_t stream)
{
    const float* q    = (const float*)d_in[0];
    const float* k    = (const float*)d_in[1];
    const float* v    = (const float*)d_in[2];
    const float* Wq   = (const float*)d_in[3];
    const float* bq   = (const float*)d_in[4];
    const float* Wk   = (const float*)d_in[5];
    const float* bk   = (const float*)d_in[6];
    const float* Wv   = (const float*)d_in[7];
    const float* bv   = (const float*)d_in[8];
    const float* memo = (const float*)d_in[9];
    float* ws   = (float*)d_ws;
    float* outp = (float*)d_out;

    hipLaunchKernelGGL(proj_kernel, dim3(6, 6, 12), dim3(256), 0, stream,
                       q, k, v, Wq, Wk, Wv, ws);
    hipLaunchKernelGGL(reduce_kernel, dim3(288), dim3(256), 0, stream, bq, bk, bv, ws);
    hipLaunchKernelGGL(mega_kernel, dim3(64, NEG), dim3(256), 0, stream, memo, ws);
    hipLaunchKernelGGL(outsum_kernel, dim3(192), dim3(256), 0, stream, ws, outp);
}

// Round 11
// 125.447 us; speedup vs baseline: 1.1229x; 1.1229x over previous
//
#include <hip/hip_runtime.h>

// Problem constants
#define H   16
#define E   300
#define D   768
#define HD  48
#define QL  64
#define KL  64
#define NH  64          // n(4) * h(16)
#define ROWS 384        // 256 Q rows + 64 K + 64 V
#define SPLITK 12
#define NEG 12          // e-chunk count (12 x 25 = 300)
#define ECH 25          // e per mega block

// Workspace float offsets
#define OFF_PP 0                              // Ppart[12][384][768]
#define OFF_PF (SPLITK*ROWS*D)                // 3,538,944  Pf[384][768]
#define OFF_OP (OFF_PF + ROWS*D)              // 3,833,856  OP[12][nh][q][48]
// end = 6,193,152 floats = 24.8 MB

// ---------------------------------------------------------------------------
// K1: QKV projection.  BM=64, BN=128, BK=32, splitK=12 (K-chunk 64).
// grid (6 rowblk, 6 colblk, 12 ks) = 432 blocks (2/CU), 256 thr, 4x8 microtile.
// (verified R3-R5 code, unchanged)
// ---------------------------------------------------------------------------
__global__ __launch_bounds__(256, 2) void proj_kernel(
    const float* __restrict__ qin, const float* __restrict__ kin, const float* __restrict__ vin,
    const float* __restrict__ Wq, const float* __restrict__ Wk, const float* __restrict__ Wv,
    float* __restrict__ ws)
{
    const int rowblk = blockIdx.x;            // 0..5 (64 rows each)
    const int col0   = blockIdx.y * 128;      // 0..640
    const int ks     = blockIdx.z;            // 0..11
    const int kbase  = ks * 64;

    const float* W = (rowblk < 4) ? Wq : (rowblk == 4) ? Wk : Wv;

    __shared__ float XsT[32][68];             // [dk][row], padded
    __shared__ float Ws[32][128];             // [dk][col]

    const int tid = threadIdx.x;
    const int r0  = (tid >> 4) * 4;           // 0..60
    const int c0  = (tid & 15) * 8;           // 0..120

    float acc[4][8];
    #pragma unroll
    for (int i = 0; i < 4; i++)
        #pragma unroll
        for (int j = 0; j < 8; j++) acc[i][j] = 0.f;

    for (int kk2 = 0; kk2 < 64; kk2 += 32) {
        // stage X tile (64 rows x 32 dk), transposed
        #pragma unroll
        for (int it = 0; it < 2; it++) {
            const int idx = it * 256 + tid;   // 0..511
            const int row = idx >> 3;         // 0..63
            const int d4  = (idx & 7) * 4;    // 0..28
            const int grow = rowblk * 64 + row;
            const float* src = (grow < 256) ? (qin + grow * D)
                             : (grow < 320) ? (kin + (grow - 256) * D)
                                            : (vin + (grow - 320) * D);
            const float4 xv = *(const float4*)(src + kbase + kk2 + d4);
            XsT[d4 + 0][row] = xv.x; XsT[d4 + 1][row] = xv.y;
            XsT[d4 + 2][row] = xv.z; XsT[d4 + 3][row] = xv.w;
        }
        // stage W tile (32 dk x 128 cols)
        #pragma unroll
        for (int it = 0; it < 4; it++) {
            const int idx = it * 256 + tid;   // 0..1023
            const int dk  = idx >> 5;         // 0..31
            const int c4  = (idx & 31) * 4;   // 0..124
            *(float4*)&Ws[dk][c4] =
                *(const float4*)(W + (kbase + kk2 + dk) * D + col0 + c4);
        }
        __syncthreads();
        #pragma unroll
        for (int dk = 0; dk < 32; dk++) {
            const float4 x0 = *(const float4*)&XsT[dk][r0];
            const float4 w0 = *(const float4*)&Ws[dk][c0];
            const float4 w1 = *(const float4*)&Ws[dk][c0 + 4];
            const float xr[4] = {x0.x, x0.y, x0.z, x0.w};
            const float wc[8] = {w0.x, w0.y, w0.z, w0.w, w1.x, w1.y, w1.z, w1.w};
            #pragma unroll
            for (int i = 0; i < 4; i++)
                #pragma unroll
                for (int j = 0; j < 8; j++)
                    acc[i][j] = fmaf(xr[i], wc[j], acc[i][j]);
        }
        __syncthreads();
    }
    float* P = ws + OFF_PP + ks * (ROWS * D);
    #pragma unroll
    for (int i = 0; i < 4; i++) {
        float* base = P + (rowblk * 64 + r0 + i) * D + col0 + c0;
        *(float4*)(base)     = make_float4(acc[i][0], acc[i][1], acc[i][2], acc[i][3]);
        *(float4*)(base + 4) = make_float4(acc[i][4], acc[i][5], acc[i][6], acc[i][7]);
    }
}

// ---------------------------------------------------------------------------
// K2: sum 12 splitK partials + bias -> Pf.  grid 288 x 256, 4 floats/thread.
// (verified R0/R5 code, unchanged)
// ---------------------------------------------------------------------------
__global__ __launch_bounds__(256) void reduce_kernel(
    const float* __restrict__ bq, const float* __restrict__ bk, const float* __restrict__ bv,
    float* __restrict__ ws)
{
    const int idx = (blockIdx.x * 256 + threadIdx.x) * 4;   // < 294912
    const float* PP = ws + OFF_PP;
    float4 v = *(const float4*)(PP + idx);
    #pragma unroll
    for (int c = 1; c < SPLITK; c++) {
        const float4 p = *(const float4*)(PP + c * (ROWS * D) + idx);
        v.x += p.x; v.y += p.y; v.z += p.z; v.w += p.w;
    }
    const int row = idx / D, col = idx % D;
    const float* bias = (row < 256) ? bq : (row < 320) ? bk : bv;
    const float4 b = *(const float4*)(bias + col);
    v.x += b.x; v.y += b.y; v.z += b.z; v.w += b.w;
    *(float4*)(ws + OFF_PF + idx) = v;
}

// ---------------------------------------------------------------------------
// K3: mega (R8 body; ONLY change vs R8: launch_bounds (256,3) -> (256,2)).
// R8's (256,3) forced VGPR 120->84 and spilled s/m/b to scratch (WRITE_SIZE
// 10->66 MB, 57 us).  At VGPR~120 the HW gives 16 waves/CU, so occupancy is
// LDS-limited: 51.2 KB -> 3 blocks/CU at runtime with no register coercion.
// grid (64,12) = 768 blocks.
// ---------------------------------------------------------------------------
__global__ __launch_bounds__(256, 2) void mega_kernel(
    const float* __restrict__ memo, float* __restrict__ ws)
{
    const int nh = blockIdx.x;
    const int eg = blockIdx.y;                // 0..11
    const int e0 = eg * ECH;
    const int ecnt = ECH;                     // 12 x 25 = 300 exact
    const int n = nh >> 4, h = nh & 15;
    const int tid = threadIdx.x;
    const int lane = tid & 63;                // k
    const int w = tid >> 6;                   // 0..3

    const float* Pf = ws + OFF_PF;

    __shared__ float U[8448];                 // 33.0 KB union region
    __shared__ float Bs[64][68];              // 17.4 KB  B [k][q]; later Vs overlay
    // total 51.2 KB -> 3 blocks/CU (LDS-limited)

    float* QsT = U;                           // [48][68]  3264 floats
    float* KsT = U + 3264;                    // [48][68]  3264 floats
    float* MsT = U + 6528;                    // [48][40]  1920 floats
    float* As  = U + 3264;                    // [25][64]  1600 floats (overlays KsT)

    // ---- stage Q,K slices (transposed) + mem chunk ----
    #pragma unroll
    for (int it = 0; it < 3; it++) {
        const int idx = it * 256 + tid;       // 0..767
        const int r  = idx / 12;              // 0..63
        const int d4 = (idx % 12) * 4;
        const float4 qv = *(const float4*)(Pf + (n * QL + r) * D + h * HD + d4);
        QsT[(d4 + 0) * 68 + r] = qv.x; QsT[(d4 + 1) * 68 + r] = qv.y;
        QsT[(d4 + 2) * 68 + r] = qv.z; QsT[(d4 + 3) * 68 + r] = qv.w;
        const float4 kv = *(const float4*)(Pf + (256 + r) * D + h * HD + d4);
        KsT[(d4 + 0) * 68 + r] = kv.x; KsT[(d4 + 1) * 68 + r] = kv.y;
        KsT[(d4 + 2) * 68 + r] = kv.z; KsT[(d4 + 3) * 68 + r] = kv.w;
    }
    for (int idx = tid; idx < ecnt * 12; idx += 256) {
        const int e  = idx / 12;
        const int d4 = (idx % 12) * 4;
        const float4 mv = *(const float4*)(memo + (e0 + e) * D + h * HD + d4);
        MsT[(d4 + 0) * 40 + e] = mv.x; MsT[(d4 + 1) * 40 + e] = mv.y;
        MsT[(d4 + 2) * 40 + e] = mv.z; MsT[(d4 + 3) * 40 + e] = mv.w;
    }
    __syncthreads();

    // ---- B[k][q] = sum_d K[k,d] * Q[q,d]  (4x4 microtile) ----
    {
        const int k0 = (tid >> 4) * 4;
        const int q0 = (tid & 15) * 4;
        float acc[4][4];
        #pragma unroll
        for (int i = 0; i < 4; i++)
            #pragma unroll
            for (int j = 0; j < 4; j++) acc[i][j] = 0.f;
        #pragma unroll 4
        for (int d = 0; d < HD; d++) {
            const float4 kf = *(const float4*)&KsT[d * 68 + k0];
            const float4 qf = *(const float4*)&QsT[d * 68 + q0];
            const float kk4[4] = {kf.x, kf.y, kf.z, kf.w};
            const float qq4[4] = {qf.x, qf.y, qf.z, qf.w};
            #pragma unroll
            for (int i = 0; i < 4; i++)
                #pragma unroll
                for (int j = 0; j < 4; j++)
                    acc[i][j] = fmaf(kk4[i], qq4[j], acc[i][j]);
        }
        #pragma unroll
        for (int i = 0; i < 4; i++)
            *(float4*)&Bs[k0 + i][q0] =
                make_float4(acc[i][0], acc[i][1], acc[i][2], acc[i][3]);
    }
    __syncthreads();                          // KsT fully consumed; As may overlay

    // ---- A[e][q] = sum_d mem[e,d] * Q[q,d]  (3x4 microtile, guard e<ecnt) ----
    {
        const int et = (tid >> 4) * 3;        // 0..45
        const int q0 = (tid & 15) * 4;
        float acc[3][4];
        #pragma unroll
        for (int i = 0; i < 3; i++)
            #pragma unroll
            for (int j = 0; j < 4; j++) acc[i][j] = 0.f;
        #pragma unroll 4
        for (int d = 0; d < HD; d++) {
            const float me0 = MsT[d * 40 + et + 0];
            const float me1 = MsT[d * 40 + et + 1];
            const float me2 = MsT[d * 40 + et + 2];
            const float4 qf = *(const float4*)&QsT[d * 68 + q0];
            const float mm3[3] = {me0, me1, me2};
            const float qq4[4] = {qf.x, qf.y, qf.z, qf.w};
            #pragma unroll
            for (int i = 0; i < 3; i++)
                #pragma unroll
                for (int j = 0; j < 4; j++)
                    acc[i][j] = fmaf(mm3[i], qq4[j], acc[i][j]);
        }
        #pragma unroll
        for (int i = 0; i < 3; i++)
            if (et + i < ecnt)
                *(float4*)&As[(et + i) * 64 + q0] =
                    make_float4(acc[i][0], acc[i][1], acc[i][2], acc[i][3]);
    }
    __syncthreads();

    // ---- B row -> registers (lane = k) ----
    float b[64];
    #pragma unroll
    for (int j = 0; j < 16; j++)
        *(float4*)&b[j * 4] = *(const float4*)&Bs[lane][j * 4];
    __syncthreads();                          // all b[] reads done before Vs overlay

    // ---- stage V into Bs region (overlay); latency hides under e-loop ----
    float* Vs = &Bs[0][0];                    // [64][52] layout (flat, stride 52)
    #pragma unroll
    for (int it = 0; it < 3; it++) {
        const int idx = it * 256 + tid;       // 0..767
        const int k  = idx / 12;
        const int d4 = (idx % 12) * 4;
        const float4 vv = *(const float4*)(Pf + (320 + k) * D + h * HD + d4);
        *(float4*)&Vs[k * 52 + d4] = vv;
    }

    // ---- e-loop (verified core) ----
    float s[64];
    #pragma unroll
    for (int j = 0; j < 64; j++) s[j] = 0.f;

    const int eBeg = (ecnt * w) >> 2;         // 0,6,12,18
    const int eEnd = (ecnt * (w + 1)) >> 2;   // 6,12,18,25
    for (int e = eBeg; e < eEnd; e++) {
        float m[64];
        #pragma unroll
        for (int j4 = 0; j4 < 16; j4++) {
            const float4 a = *(const float4*)&As[e * 64 + j4 * 4];  // broadcast
            m[j4 * 4 + 0] = fmaxf(a.x + b[j4 * 4 + 0], 0.f);
            m[j4 * 4 + 1] = fmaxf(a.y + b[j4 * 4 + 1], 0.f);
            m[j4 * 4 + 2] = fmaxf(a.z + b[j4 * 4 + 2], 0.f);
            m[j4 * 4 + 3] = fmaxf(a.w + b[j4 * 4 + 3], 0.f);
        }
        float p0 = 0.f, p1 = 0.f, p2 = 0.f, p3 = 0.f;
        #pragma unroll
        for (int j4 = 0; j4 < 16; j4++) {
            p0 += m[j4 * 4 + 0]; p1 += m[j4 * 4 + 1];
            p2 += m[j4 * 4 + 2]; p3 += m[j4 * 4 + 3];
        }
        const float p = (p0 + p1) + (p2 + p3);
        #pragma unroll
        for (int j = 0; j < 64; j++)
            s[j] = fmaf(m[j], p, s[j]);
    }

    // ---- sequential 1-buffer wave reduce (r = 16 KB in U; As dead) ----
    float* r = U;                             // [0, 4096)
    float* Ss = U + 4096;                     // [64][68] = 4352 -> [4096, 8448)
    __syncthreads();
    if (w == 2) {
        #pragma unroll
        for (int q = 0; q < 64; q++) r[q * 64 + lane] = s[q];
    }
    __syncthreads();
    if (w == 0) {
        #pragma unroll
        for (int q = 0; q < 64; q++) s[q] += r[q * 64 + lane];
    }
    __syncthreads();
    if (w == 3) {
        #pragma unroll
        for (int q = 0; q < 64; q++) r[q * 64 + lane] = s[q];
    }
    __syncthreads();
    if (w == 1) {
        #pragma unroll
        for (int q = 0; q < 64; q++) s[q] += r[q * 64 + lane];
    }
    __syncthreads();
    if (w == 1) {
        #pragma unroll
        for (int q = 0; q < 64; q++) r[q * 64 + lane] = s[q];
    }
    __syncthreads();
    if (w == 0) {
        #pragma unroll
        for (int q = 0; q < 64; q++)
            Ss[q * 68 + lane] = s[q] + r[q * 64 + lane];
    }
    __syncthreads();

    // ---- out-partial[q][48] = sum_k Ss[q][k] * Vs[k][*] ----
    {
        const int q  = tid >> 2;              // 0..63
        const int dg = tid & 3;               // 0..3 (12 d each)
        float4 a0 = make_float4(0.f, 0.f, 0.f, 0.f);
        float4 a1 = a0, a2 = a0;
        #pragma unroll 8
        for (int k = 0; k < KL; k++) {
            const float sv = Ss[q * 68 + k];
            const float4 v0 = *(const float4*)&Vs[k * 52 + dg * 12 + 0];
            const float4 v1 = *(const float4*)&Vs[k * 52 + dg * 12 + 4];
            const float4 v2 = *(const float4*)&Vs[k * 52 + dg * 12 + 8];
            a0.x = fmaf(sv, v0.x, a0.x); a0.y = fmaf(sv, v0.y, a0.y);
            a0.z = fmaf(sv, v0.z, a0.z); a0.w = fmaf(sv, v0.w, a0.w);
            a1.x = fmaf(sv, v1.x, a1.x); a1.y = fmaf(sv, v1.y, a1.y);
            a1.z = fmaf(sv, v1.z, a1.z); a1.w = fmaf(sv, v1.w, a1.w);
            a2.x = fmaf(sv, v2.x, a2.x); a2.y = fmaf(sv, v2.y, a2.y);
            a2.z = fmaf(sv, v2.z, a2.z); a2.w = fmaf(sv, v2.w, a2.w);
        }
        float* OP = ws + OFF_OP + (((eg * NH) + nh) * QL + q) * 48 + dg * 12;
        *(float4*)(OP + 0) = a0;
        *(float4*)(OP + 4) = a1;
        *(float4*)(OP + 8) = a2;
    }
}

// ---------------------------------------------------------------------------
// K4: out = sum of 12 out-partials.  grid 192 x 256, one float4/thread.
// (verified R5/R8 code)
// ---------------------------------------------------------------------------
__global__ __launch_bounds__(256) void outsum_kernel(
    const float* __restrict__ ws_c, float* __restrict__ outp)
{
    const int g = blockIdx.x * 256 + threadIdx.x;   // 0..49151
    const int d12 = g % 12;
    const int q   = (g / 12) & 63;
    const int nh  = g / 768;                        // 0..63
    const int n = nh >> 4, h = nh & 15;
    const float* OP = ws_c + OFF_OP;

    float4 acc = make_float4(0.f, 0.f, 0.f, 0.f);
    #pragma unroll
    for (int c = 0; c < NEG; c++) {
        const float4 p = *(const float4*)(OP + c * (NH * QL * 48)
                                          + (nh * QL + q) * 48 + d12 * 4);
        acc.x += p.x; acc.y += p.y; acc.z += p.z; acc.w += p.w;
    }
    *(float4*)(outp + (n * QL + q) * D + h * HD + d12 * 4) = acc;
}

// ---------------------------------------------------------------------------
extern "C" void kernel_launch(void* const* d_in, const int* in_sizes, int n_in,
                              void* d_out, int out_size, void* d_ws, size_t ws_size,
                              hipStream_t stream)
{
    const float* q    = (const float*)d_in[0];
    const float* k    = (const float*)d_in[1];
    const float* v    = (const float*)d_in[2];
    const float* Wq   = (const float*)d_in[3];
    const float* bq   = (const float*)d_in[4];
    const float* Wk   = (const float*)d_in[5];
    const float* bk   = (const float*)d_in[6];
    const float* Wv   = (const float*)d_in[7];
    const float* bv   = (const float*)d_in[8];
    const float* memo = (const float*)d_in[9];
    float* ws   = (float*)d_ws;
    float* outp = (float*)d_out;

    hipLaunchKernelGGL(proj_kernel, dim3(6, 6, 12), dim3(256), 0, stream,
                       q, k, v, Wq, Wk, Wv, ws);
    hipLaunchKernelGGL(reduce_kernel, dim3(288), dim3(256), 0, stream, bq, bk, bv, ws);
    hipLaunchKernelGGL(mega_kernel, dim3(64, NEG), dim3(256), 0, stream, memo, ws);
    hipLaunchKernelGGL(outsum_kernel, dim3(192), dim3(256), 0, stream, ws, outp);
}

// Round 12
// 116.760 us; speedup vs baseline: 1.2065x; 1.0744x over previous
//
#include <hip/hip_runtime.h>

// Problem constants
#define H   16
#define E   300
#define D   768
#define HD  48
#define QL  64
#define KL  64
#define NH  64          // n(4) * h(16)
#define ROWS 384        // 256 Q rows + 64 K + 64 V
#define SPLITK 12
#define NEG 8           // e-chunk count
#define ECH 38          // e per mega block (last block: 34)

// Workspace float offsets
#define OFF_PP 0                              // Ppart[12][384][768]
#define OFF_PF (SPLITK*ROWS*D)                // 3,538,944  Pf[384][768]
#define OFF_OP (OFF_PF + ROWS*D)              // 3,833,856  OP[8][nh][q][48]
// end = 5,406,720 floats = 21.6 MB

// ---------------------------------------------------------------------------
// K1: QKV projection.  BM=64, BN=128, BK=32, splitK=12 (K-chunk 64).
// grid (6 rowblk, 6 colblk, 12 ks) = 432 blocks (2/CU), 256 thr, 4x8 microtile.
// (verified R3/R5 code, unchanged)
// ---------------------------------------------------------------------------
__global__ __launch_bounds__(256, 2) void proj_kernel(
    const float* __restrict__ qin, const float* __restrict__ kin, const float* __restrict__ vin,
    const float* __restrict__ Wq, const float* __restrict__ Wk, const float* __restrict__ Wv,
    float* __restrict__ ws)
{
    const int rowblk = blockIdx.x;            // 0..5 (64 rows each)
    const int col0   = blockIdx.y * 128;      // 0..640
    const int ks     = blockIdx.z;            // 0..11
    const int kbase  = ks * 64;

    const float* W = (rowblk < 4) ? Wq : (rowblk == 4) ? Wk : Wv;

    __shared__ float XsT[32][68];             // [dk][row], padded
    __shared__ float Ws[32][128];             // [dk][col]

    const int tid = threadIdx.x;
    const int r0  = (tid >> 4) * 4;           // 0..60
    const int c0  = (tid & 15) * 8;           // 0..120

    float acc[4][8];
    #pragma unroll
    for (int i = 0; i < 4; i++)
        #pragma unroll
        for (int j = 0; j < 8; j++) acc[i][j] = 0.f;

    for (int kk2 = 0; kk2 < 64; kk2 += 32) {
        // stage X tile (64 rows x 32 dk), transposed
        #pragma unroll
        for (int it = 0; it < 2; it++) {
            const int idx = it * 256 + tid;   // 0..511
            const int row = idx >> 3;         // 0..63
            const int d4  = (idx & 7) * 4;    // 0..28
            const int grow = rowblk * 64 + row;
            const float* src = (grow < 256) ? (qin + grow * D)
                             : (grow < 320) ? (kin + (grow - 256) * D)
                                            : (vin + (grow - 320) * D);
            const float4 xv = *(const float4*)(src + kbase + kk2 + d4);
            XsT[d4 + 0][row] = xv.x; XsT[d4 + 1][row] = xv.y;
            XsT[d4 + 2][row] = xv.z; XsT[d4 + 3][row] = xv.w;
        }
        // stage W tile (32 dk x 128 cols)
        #pragma unroll
        for (int it = 0; it < 4; it++) {
            const int idx = it * 256 + tid;   // 0..1023
            const int dk  = idx >> 5;         // 0..31
            const int c4  = (idx & 31) * 4;   // 0..124
            *(float4*)&Ws[dk][c4] =
                *(const float4*)(W + (kbase + kk2 + dk) * D + col0 + c4);
        }
        __syncthreads();
        #pragma unroll
        for (int dk = 0; dk < 32; dk++) {
            const float4 x0 = *(const float4*)&XsT[dk][r0];
            const float4 w0 = *(const float4*)&Ws[dk][c0];
            const float4 w1 = *(const float4*)&Ws[dk][c0 + 4];
            const float xr[4] = {x0.x, x0.y, x0.z, x0.w};
            const float wc[8] = {w0.x, w0.y, w0.z, w0.w, w1.x, w1.y, w1.z, w1.w};
            #pragma unroll
            for (int i = 0; i < 4; i++)
                #pragma unroll
                for (int j = 0; j < 8; j++)
                    acc[i][j] = fmaf(xr[i], wc[j], acc[i][j]);
        }
        __syncthreads();
    }
    float* P = ws + OFF_PP + ks * (ROWS * D);
    #pragma unroll
    for (int i = 0; i < 4; i++) {
        float* base = P + (rowblk * 64 + r0 + i) * D + col0 + c0;
        *(float4*)(base)     = make_float4(acc[i][0], acc[i][1], acc[i][2], acc[i][3]);
        *(float4*)(base + 4) = make_float4(acc[i][4], acc[i][5], acc[i][6], acc[i][7]);
    }
}

// ---------------------------------------------------------------------------
// K2: sum 12 splitK partials + bias -> Pf.  grid 288 x 256, 4 floats/thread.
// (verified R0/R5 code, unchanged)
// ---------------------------------------------------------------------------
__global__ __launch_bounds__(256) void reduce_kernel(
    const float* __restrict__ bq, const float* __restrict__ bk, const float* __restrict__ bv,
    float* __restrict__ ws)
{
    const int idx = (blockIdx.x * 256 + threadIdx.x) * 4;   // < 294912
    const float* PP = ws + OFF_PP;
    float4 v = *(const float4*)(PP + idx);
    #pragma unroll
    for (int c = 1; c < SPLITK; c++) {
        const float4 p = *(const float4*)(PP + c * (ROWS * D) + idx);
        v.x += p.x; v.y += p.y; v.z += p.z; v.w += p.w;
    }
    const int row = idx / D, col = idx % D;
    const float* bias = (row < 256) ? bq : (row < 320) ? bk : bv;
    const float4 b = *(const float4*)(bias + col);
    v.x += b.x; v.y += b.y; v.z += b.z; v.w += b.w;
    *(float4*)(ws + OFF_PF + idx) = v;
}

// ---------------------------------------------------------------------------
// K3: mega (verified R5 body, byte-identical).  Block = (nh, eg of up to 38 e).
// Stage Q/K/mem -> build B (64x64) and A-chunk in LDS -> e-loop -> 4-wave
// parallel LDS tree reduce -> out-partial = Ss.V -> OP[eg][nh].
// grid (64, 8) = 512 blocks, 2 blocks/CU (LDS ~61.5 KB).
// ---------------------------------------------------------------------------
__global__ __launch_bounds__(256, 2) void mega_kernel(
    const float* __restrict__ memo, float* __restrict__ ws)
{
    const int nh = blockIdx.x;
    const int eg = blockIdx.y;                // 0..7
    const int e0 = eg * ECH;
    const int ecnt = (E - e0 < ECH) ? (E - e0) : ECH;   // 38 or 34
    const int n = nh >> 4, h = nh & 15;
    const int tid = threadIdx.x;
    const int lane = tid & 63;                // k
    const int w = tid >> 6;                   // 0..3

    const float* Pf = ws + OFF_PF;

    __shared__ float As[ECH * 64];            // 9.5 KB   A-chunk [e][q]
    __shared__ float Bs[64][68];              // 17.4 KB  B [k][q]; later Vs overlay
    __shared__ float U[8832];                 // 34.5 KB  union region

    float* QsT = U;                           // [48][68] (d-major)
    float* KsT = U + 48 * 68;                 // [48][68]
    float* MsT = U + 2 * 48 * 68;             // [48][40]

    // ---- stage Q,K slices (transposed) + mem chunk ----
    #pragma unroll
    for (int it = 0; it < 3; it++) {
        const int idx = it * 256 + tid;       // 0..767
        const int r  = idx / 12;              // 0..63
        const int d4 = (idx % 12) * 4;
        const float4 qv = *(const float4*)(Pf + (n * QL + r) * D + h * HD + d4);
        QsT[(d4 + 0) * 68 + r] = qv.x; QsT[(d4 + 1) * 68 + r] = qv.y;
        QsT[(d4 + 2) * 68 + r] = qv.z; QsT[(d4 + 3) * 68 + r] = qv.w;
        const float4 kv = *(const float4*)(Pf + (256 + r) * D + h * HD + d4);
        KsT[(d4 + 0) * 68 + r] = kv.x; KsT[(d4 + 1) * 68 + r] = kv.y;
        KsT[(d4 + 2) * 68 + r] = kv.z; KsT[(d4 + 3) * 68 + r] = kv.w;
    }
    for (int idx = tid; idx < ecnt * 12; idx += 256) {
        const int e  = idx / 12;
        const int d4 = (idx % 12) * 4;
        const float4 mv = *(const float4*)(memo + (e0 + e) * D + h * HD + d4);
        MsT[(d4 + 0) * 40 + e] = mv.x; MsT[(d4 + 1) * 40 + e] = mv.y;
        MsT[(d4 + 2) * 40 + e] = mv.z; MsT[(d4 + 3) * 40 + e] = mv.w;
    }
    __syncthreads();

    // ---- B[k][q] = sum_d K[k,d] * Q[q,d]  (4x4 microtile) ----
    {
        const int k0 = (tid >> 4) * 4;
        const int q0 = (tid & 15) * 4;
        float acc[4][4];
        #pragma unroll
        for (int i = 0; i < 4; i++)
            #pragma unroll
            for (int j = 0; j < 4; j++) acc[i][j] = 0.f;
        #pragma unroll 4
        for (int d = 0; d < HD; d++) {
            const float4 kf = *(const float4*)&KsT[d * 68 + k0];
            const float4 qf = *(const float4*)&QsT[d * 68 + q0];
            const float kk4[4] = {kf.x, kf.y, kf.z, kf.w};
            const float qq4[4] = {qf.x, qf.y, qf.z, qf.w};
            #pragma unroll
            for (int i = 0; i < 4; i++)
                #pragma unroll
                for (int j = 0; j < 4; j++)
                    acc[i][j] = fmaf(kk4[i], qq4[j], acc[i][j]);
        }
        #pragma unroll
        for (int i = 0; i < 4; i++)
            *(float4*)&Bs[k0 + i][q0] =
                make_float4(acc[i][0], acc[i][1], acc[i][2], acc[i][3]);
    }
    // ---- A[e][q] = sum_d mem[e,d] * Q[q,d]  (3x4 microtile, guard e<ecnt) ----
    {
        const int et = (tid >> 4) * 3;        // 0..45
        const int q0 = (tid & 15) * 4;
        float acc[3][4];
        #pragma unroll
        for (int i = 0; i < 3; i++)
            #pragma unroll
            for (int j = 0; j < 4; j++) acc[i][j] = 0.f;
        #pragma unroll 4
        for (int d = 0; d < HD; d++) {
            const float me0 = MsT[d * 40 + et + 0];
            const float me1 = MsT[d * 40 + et + 1];
            const float me2 = MsT[d * 40 + et + 2];
            const float4 qf = *(const float4*)&QsT[d * 68 + q0];
            const float mm3[3] = {me0, me1, me2};
            const float qq4[4] = {qf.x, qf.y, qf.z, qf.w};
            #pragma unroll
            for (int i = 0; i < 3; i++)
                #pragma unroll
                for (int j = 0; j < 4; j++)
                    acc[i][j] = fmaf(mm3[i], qq4[j], acc[i][j]);
        }
        #pragma unroll
        for (int i = 0; i < 3; i++)
            if (et + i < ecnt)
                *(float4*)&As[(et + i) * 64 + q0] =
                    make_float4(acc[i][0], acc[i][1], acc[i][2], acc[i][3]);
    }
    __syncthreads();

    // ---- B row -> registers (lane = k) ----
    float b[64];
    #pragma unroll
    for (int j = 0; j < 16; j++)
        *(float4*)&b[j * 4] = *(const float4*)&Bs[lane][j * 4];
    __syncthreads();                          // all b[] reads done before Vs overlay

    // ---- stage V into Bs region (overlay); latency hides under e-loop ----
    float* Vs = &Bs[0][0];                    // [64][52] layout (flat, stride 52)
    #pragma unroll
    for (int it = 0; it < 3; it++) {
        const int idx = it * 256 + tid;       // 0..767
        const int k  = idx / 12;
        const int d4 = (idx % 12) * 4;
        const float4 vv = *(const float4*)(Pf + (320 + k) * D + h * HD + d4);
        *(float4*)&Vs[k * 52 + d4] = vv;
    }

    // ---- e-loop (verified core) ----
    float s[64];
    #pragma unroll
    for (int j = 0; j < 64; j++) s[j] = 0.f;

    const int eBeg = (ecnt * w) >> 2;
    const int eEnd = (ecnt * (w + 1)) >> 2;
    for (int e = eBeg; e < eEnd; e++) {
        float m[64];
        #pragma unroll
        for (int j4 = 0; j4 < 16; j4++) {
            const float4 a = *(const float4*)&As[e * 64 + j4 * 4];  // broadcast
            m[j4 * 4 + 0] = fmaxf(a.x + b[j4 * 4 + 0], 0.f);
            m[j4 * 4 + 1] = fmaxf(a.y + b[j4 * 4 + 1], 0.f);
            m[j4 * 4 + 2] = fmaxf(a.z + b[j4 * 4 + 2], 0.f);
            m[j4 * 4 + 3] = fmaxf(a.w + b[j4 * 4 + 3], 0.f);
        }
        float p0 = 0.f, p1 = 0.f, p2 = 0.f, p3 = 0.f;
        #pragma unroll
        for (int j4 = 0; j4 < 16; j4++) {
            p0 += m[j4 * 4 + 0]; p1 += m[j4 * 4 + 1];
            p2 += m[j4 * 4 + 2]; p3 += m[j4 * 4 + 3];
        }
        const float p = (p0 + p1) + (p2 + p3);
        #pragma unroll
        for (int j = 0; j < 64; j++)
            s[j] = fmaf(m[j], p, s[j]);
    }

    // ---- 4-wave tree reduce (verified) into Ss[64][68] ----
    float* r0 = U;                            // 16 KB
    float* r1 = U + 4096;                     // 16 KB
    float* Ss = U + 4096;                     // [64][68]; overlays r1 after consumed
    __syncthreads();
    if (w >= 2) {
        float* red = (w == 2) ? r0 : r1;
        #pragma unroll
        for (int q = 0; q < 64; q++) red[q * 64 + lane] = s[q];
    }
    __syncthreads();
    if (w == 0) {
        #pragma unroll
        for (int q = 0; q < 64; q++) s[q] += r0[q * 64 + lane];
    } else if (w == 1) {
        #pragma unroll
        for (int q = 0; q < 64; q++) s[q] += r1[q * 64 + lane];
    }
    __syncthreads();
    if (w == 1) {
        #pragma unroll
        for (int q = 0; q < 64; q++) r0[q * 64 + lane] = s[q];
    }
    __syncthreads();
    if (w == 0) {
        #pragma unroll
        for (int q = 0; q < 64; q++)
            Ss[q * 68 + lane] = s[q] + r0[q * 64 + lane];
    }
    __syncthreads();

    // ---- out-partial[q][48] = sum_k Ss[q][k] * Vs[k][*] ----
    {
        const int q  = tid >> 2;              // 0..63
        const int dg = tid & 3;               // 0..3 (12 d each)
        float4 a0 = make_float4(0.f, 0.f, 0.f, 0.f);
        float4 a1 = a0, a2 = a0;
        #pragma unroll 8
        for (int k = 0; k < KL; k++) {
            const float sv = Ss[q * 68 + k];
            const float4 v0 = *(const float4*)&Vs[k * 52 + dg * 12 + 0];
            const float4 v1 = *(const float4*)&Vs[k * 52 + dg * 12 + 4];
            const float4 v2 = *(const float4*)&Vs[k * 52 + dg * 12 + 8];
            a0.x = fmaf(sv, v0.x, a0.x); a0.y = fmaf(sv, v0.y, a0.y);
            a0.z = fmaf(sv, v0.z, a0.z); a0.w = fmaf(sv, v0.w, a0.w);
            a1.x = fmaf(sv, v1.x, a1.x); a1.y = fmaf(sv, v1.y, a1.y);
            a1.z = fmaf(sv, v1.z, a1.z); a1.w = fmaf(sv, v1.w, a1.w);
            a2.x = fmaf(sv, v2.x, a2.x); a2.y = fmaf(sv, v2.y, a2.y);
            a2.z = fmaf(sv, v2.z, a2.z); a2.w = fmaf(sv, v2.w, a2.w);
        }
        float* OP = ws + OFF_OP + (((eg * NH) + nh) * QL + q) * 48 + dg * 12;
        *(float4*)(OP + 0) = a0;
        *(float4*)(OP + 4) = a1;
        *(float4*)(OP + 8) = a2;
    }
}

// ---------------------------------------------------------------------------
// K4: out = sum of 8 out-partials.  grid 192 x 256, one float4/thread.
// (verified R5 code, unchanged)
// ---------------------------------------------------------------------------
__global__ __launch_bounds__(256) void outsum_kernel(
    const float* __restrict__ ws_c, float* __restrict__ outp)
{
    const int g = blockIdx.x * 256 + threadIdx.x;   // 0..49151
    const int d12 = g % 12;
    const int q   = (g / 12) & 63;
    const int nh  = g / 768;                        // 0..63
    const int n = nh >> 4, h = nh & 15;
    const float* OP = ws_c + OFF_OP;

    float4 acc = make_float4(0.f, 0.f, 0.f, 0.f);
    #pragma unroll
    for (int c = 0; c < NEG; c++) {
        const float4 p = *(const float4*)(OP + c * (NH * QL * 48)
                                          + (nh * QL + q) * 48 + d12 * 4);
        acc.x += p.x; acc.y += p.y; acc.z += p.z; acc.w += p.w;
    }
    *(float4*)(outp + (n * QL + q) * D + h * HD + d12 * 4) = acc;
}

// ---------------------------------------------------------------------------
extern "C" void kernel_launch(void* const* d_in, const int* in_sizes, int n_in,
                              void* d_out, int out_size, void* d_ws, size_t ws_size,
                              hipStream_t stream)
{
    const float* q    = (const float*)d_in[0];
    const float* k    = (const float*)d_in[1];
    const float* v    = (const float*)d_in[2];
    const float* Wq   = (const float*)d_in[3];
    const float* bq   = (const float*)d_in[4];
    const float* Wk   = (const float*)d_in[5];
    const float* bk   = (const float*)d_in[6];
    const float* Wv   = (const float*)d_in[7];
    const float* bv   = (const float*)d_in[8];
    const float* memo = (const float*)d_in[9];
    float* ws   = (float*)d_ws;
    float* outp = (float*)d_out;

    hipLaunchKernelGGL(proj_kernel, dim3(6, 6, 12), dim3(256), 0, stream,
                       q, k, v, Wq, Wk, Wv, ws);
    hipLaunchKernelGGL(reduce_kernel, dim3(288), dim3(256), 0, stream, bq, bk, bv, ws);
    hipLaunchKernelGGL(mega_kernel, dim3(64, NEG), dim3(256), 0, stream, memo, ws);
    hipLaunchKernelGGL(outsum_kernel, dim3(192), dim3(256), 0, stream, ws, outp);
}